// Round 6
// baseline (259.193 us; speedup 1.0000x reference)
//
#include <hip/hip_runtime.h>
#include <math.h>

#define NB   4
#define NN   2048
#define DD   512
#define NOUT 512
#define NH   8
#define HDIM 64

typedef __attribute__((ext_vector_type(4))) short bf16x4;
typedef __attribute__((ext_vector_type(8))) short bf16x8;
typedef __attribute__((ext_vector_type(4))) float f32x4;
#define MFMA32(a, b, c)  __builtin_amdgcn_mfma_f32_16x16x32_bf16(a, b, c, 0, 0, 0)
#define MFMA16(a, b, c)  __builtin_amdgcn_mfma_f32_16x16x16bf16_1k(a, b, c, 0, 0, 0)

typedef const __attribute__((address_space(1))) unsigned int* gas_ptr;
typedef __attribute__((address_space(3))) unsigned int* las_ptr;

#define SCALE2 0.18033688f   /* 8^-1 * log2(e) */

__device__ inline unsigned short f2bf(float f) {
    unsigned int u = __float_as_uint(f);
    u += 0x7fffu + ((u >> 16) & 1u);   // RNE
    return (unsigned short)(u >> 16);
}

// pack two fp32 -> two bf16 (truncation) in ONE v_perm
__device__ inline unsigned int pack_trunc(float lo, float hi) {
    return __builtin_amdgcn_perm(__float_as_uint(hi), __float_as_uint(lo), 0x07060302u);
}

// ---------------------------------------------------------------------------
// prep: fused convx (x->bf16), transW (4 weights -> bf16 transposed),
// pack_adj (adj -> bit mask, TRANSPOSED layout bitsT[word][row]).
// ---------------------------------------------------------------------------
__global__ __launch_bounds__(256) void prep(
    const float* __restrict__ x, unsigned short* __restrict__ xb,
    const float* __restrict__ W0, const float* __restrict__ W1,
    const float* __restrict__ W2, const float* __restrict__ W3,
    unsigned short* __restrict__ T0, unsigned short* __restrict__ T1,
    unsigned short* __restrict__ T2, unsigned short* __restrict__ T3,
    const int* __restrict__ adj, unsigned long long* __restrict__ bitsT)
{
    const int blk = blockIdx.x;
    const int t   = threadIdx.x;

    if (blk < 2048) {                       // ---- convx: 8 floats/thread ----
        const int i = (blk * 256 + t) * 8;
        float4 a = *(const float4*)(x + i);
        float4 b = *(const float4*)(x + i + 4);
        ushort4 u0, u1;
        u0.x = f2bf(a.x); u0.y = f2bf(a.y); u0.z = f2bf(a.z); u0.w = f2bf(a.w);
        u1.x = f2bf(b.x); u1.y = f2bf(b.y); u1.z = f2bf(b.z); u1.w = f2bf(b.w);
        *(ushort4*)(xb + i)     = u0;
        *(ushort4*)(xb + i + 4) = u1;
        return;
    }
    if (blk < 2304) {                       // ---- transW ----
        __shared__ float tile[64][65];
        const int idx = blk - 2048;
        const int z = idx >> 6, rem = idx & 63;
        const float* W; unsigned short* T;
        switch (z) {
            case 0:  W = W0; T = T0; break;
            case 1:  W = W1; T = T1; break;
            case 2:  W = W2; T = T2; break;
            default: W = W3; T = T3; break;
        }
        const int k0 = (rem & 7) * 64, n0 = (rem >> 3) * 64;
        const int r = t >> 6, c = t & 63;
#pragma unroll
        for (int rep = 0; rep < 16; ++rep) {
            const int row = rep * 4 + r;
            tile[row][c] = W[(size_t)(k0 + row) * NOUT + n0 + c];
        }
        __syncthreads();
#pragma unroll
        for (int rep = 0; rep < 16; ++rep) {
            const int row = rep * 4 + r;          // n index
            T[(size_t)(n0 + row) * DD + k0 + c] = f2bf(tile[c][row]);
        }
        return;
    }
    // ---- pack_adj: bitsT[word*2048 + row] ----
    {
        const int idx  = blk - 2304;
        const int wave = t >> 6, lane = t & 63;
        const int j    = idx * 4 + wave;          // 0..8191
        const int row  = j >> 2;
        const int wb   = (j & 3) * 8;
#pragma unroll
        for (int w = 0; w < 8; ++w) {
            const unsigned long long m =
                __ballot(adj[(size_t)row * NN + (wb + w) * 64 + lane] != 0);
            if (lane == 0) bitsT[(size_t)(wb + w) * NN + row] = m;
        }
    }
}

// ---------------------------------------------------------------------------
// Direct-from-global MFMA GEMM (no LDS, no barriers) — right shape for
// K=512 small-K: fragment loads hit L2 (A reused across N-tiles, Wt across
// M-tiles); 16 K-steps of 16 MFMA each, unroll-4 gives VMEM/MFMA overlap.
// Block = 4 waves, 128x128 tile, wave = 64x64.
// ---------------------------------------------------------------------------
#define GD_SETUP()                                                             \
    const int t = threadIdx.x, wave = t >> 6, lane = t & 63;                   \
    const int quad = lane >> 4, l16 = lane & 15;                               \
    const int n0 = blockIdx.x * 128, m0 = blockIdx.y * 128;                    \
    const int wm = (wave & 1) * 64, wn = (wave >> 1) * 64;                     \
    const unsigned short* aP[4];                                               \
    const unsigned short* bP[4];                                               \
    _Pragma("unroll")                                                          \
    for (int mt = 0; mt < 4; ++mt)                                             \
        aP[mt] = A  + (size_t)(m0 + wm + mt * 16 + l16) * DD + quad * 8;       \
    _Pragma("unroll")                                                          \
    for (int nt = 0; nt < 4; ++nt)                                             \
        bP[nt] = Wt + (size_t)(n0 + wn + nt * 16 + l16) * DD + quad * 8;       \
    f32x4 acc[4][4];                                                           \
    _Pragma("unroll")                                                          \
    for (int mt = 0; mt < 4; ++mt)                                             \
        _Pragma("unroll")                                                      \
        for (int nt = 0; nt < 4; ++nt) acc[mt][nt] = (f32x4){0.f, 0.f, 0.f, 0.f}; \
    _Pragma("unroll 4")                                                        \
    for (int kb = 0; kb < DD / 32; ++kb) {                                     \
        bf16x8 aF[4], bF[4];                                                   \
        _Pragma("unroll")                                                      \
        for (int mt = 0; mt < 4; ++mt) aF[mt] = *(const bf16x8*)(aP[mt] + kb * 32); \
        _Pragma("unroll")                                                      \
        for (int nt = 0; nt < 4; ++nt) bF[nt] = *(const bf16x8*)(bP[nt] + kb * 32); \
        _Pragma("unroll")                                                      \
        for (int mt = 0; mt < 4; ++mt)                                         \
            _Pragma("unroll")                                                  \
            for (int nt = 0; nt < 4; ++nt)                                     \
                acc[mt][nt] = MFMA32(aF[mt], bF[nt], acc[mt][nt]);             \
    }

// ---------------------------------------------------------------------------
// Fused QKV GEMM: [8192,512] @ Wt_cat[1536][512]^T.
// seg0 -> q bf16 [B,H,N,64] PRE-SCALED by SCALE2; seg1 -> k; seg2 -> v^T.
// ---------------------------------------------------------------------------
__global__ __launch_bounds__(256) void gemm_qkv(
    const unsigned short* __restrict__ A,
    const unsigned short* __restrict__ Wt,
    const float* __restrict__ bq, const float* __restrict__ bk,
    const float* __restrict__ bv,
    unsigned short* __restrict__ qo, unsigned short* __restrict__ ko,
    unsigned short* __restrict__ vto)
{
    GD_SETUP();

    const int seg   = n0 >> 9;           // 0:q 1:k 2:v
    const int nloc0 = n0 & 511;
    const float* bp = (seg == 0) ? bq : (seg == 1) ? bk : bv;
    unsigned short* dst3 = (seg == 0) ? qo : (seg == 1) ? ko : vto;

    float bias4[4];
#pragma unroll
    for (int nt = 0; nt < 4; ++nt) bias4[nt] = bp[nloc0 + wn + nt * 16 + l16];

#pragma unroll
    for (int mt = 0; mt < 4; ++mt) {
#pragma unroll
        for (int nt = 0; nt < 4; ++nt) {
            const int lcol = nloc0 + wn + nt * 16 + l16;
            const int h = lcol >> 6, d = lcol & 63;
#pragma unroll
            for (int r = 0; r < 4; ++r) {
                const int row = m0 + wm + mt * 16 + quad * 4 + r;
                const int bb = row >> 11, n = row & (NN - 1);
                float val = acc[mt][nt][r] + bias4[nt];
                if (seg == 0) val *= SCALE2;
                if (seg < 2)
                    dst3[((size_t)(bb * NH + h) * NN + n) * HDIM + d] = f2bf(val);
                else
                    dst3[((size_t)(bb * NH + h) * HDIM + d) * NN + n] = f2bf(val);
            }
        }
    }
}

// ---------------------------------------------------------------------------
// O-projection GEMM: out fp32 [8192,512]
// ---------------------------------------------------------------------------
__global__ __launch_bounds__(256) void gemm_o(
    const unsigned short* __restrict__ A,
    const unsigned short* __restrict__ Wt,
    const float* __restrict__ bias,
    float* __restrict__ C)
{
    GD_SETUP();

    float bias4[4];
#pragma unroll
    for (int nt = 0; nt < 4; ++nt) bias4[nt] = bias[n0 + wn + nt * 16 + l16];

#pragma unroll
    for (int mt = 0; mt < 4; ++mt)
#pragma unroll
        for (int nt = 0; nt < 4; ++nt) {
            const int col = n0 + wn + nt * 16 + l16;
#pragma unroll
            for (int r = 0; r < 4; ++r) {
                const int row = m0 + wm + mt * 16 + quad * 4 + r;
                C[(size_t)row * NOUT + col] = acc[mt][nt][r] + bias4[nt];
            }
        }
}

// ---------------------------------------------------------------------------
// MFMA flash attention, transposed-score formulation, 8-wave blocks
// (128 queries/block -> K/V staging amortized 2x, 16 waves/CU).
// S^T = mfma32(A=K, B=Q): lane holds (key=quad*4+r, q=l16); P^T registers
// feed mfma16's B operand directly. O^T[dt] = mfma16(A=V^T frag, B=Pt);
// l = mfma16(ones, Pt). K/V double-buffered, prefetch overlaps compute.
// ---------------------------------------------------------------------------
__global__ __launch_bounds__(512) void attn_mfma(
    const unsigned short* __restrict__ qg,
    const unsigned short* __restrict__ kg,
    const unsigned short* __restrict__ vt,
    const unsigned long long* __restrict__ bitT,   // [word][row]
    unsigned short* __restrict__ ao)
{
    __shared__ unsigned short smem[4 * 64 * 64];   // Ka | Va | Kb | Vb (32 KB)
    unsigned short* Ka = smem;
    unsigned short* Va = smem + 4096;
    unsigned short* Kb = smem + 8192;
    unsigned short* Vb = smem + 12288;

    const int t    = threadIdx.x;
    const int wave = t >> 6;
    const int lane = t & 63;
    const int quad = lane >> 4;
    const int l16  = lane & 15;

    const int qt = blockIdx.x, h = blockIdx.y, b = blockIdx.z;
    const int bh = b * NH + h;
    const int q0 = qt * 128;

    const unsigned short* kbase  = kg + (size_t)bh * NN * HDIM;
    const unsigned short* vtbase = vt + (size_t)bh * HDIM * NN;

    // DMA swizzle (16B blocks): physical blk = logical blk ^ (row & 7)
    const int drow = lane >> 3;              // 0..7: row within wave's 8 rows
    const int dblk = (lane & 7) ^ drow;

    // fragment-read swizzle offsets
    const int sw  = l16 & 7;
    const int bo0 = (quad ^ sw) * 8;         // K chunk0 (16B)
    const int bo1 = bo0 ^ 32;                // K chunk1
    int vofs[4];
#pragma unroll
    for (int c = 0; c < 4; ++c)
        vofs[c] = (((c * 2 + (quad >> 1)) ^ sw) * 8) + (quad & 1) * 4;  // V 8B frags

    // 8 waves x 8 rows = 64 rows; one DMA for K + one for V per lane
#define ATT_ISSUE(kt, Kd, Vd)                                                  \
    {                                                                          \
        const int r0 = wave * 8;                                               \
        __builtin_amdgcn_global_load_lds(                                      \
            (gas_ptr)(kbase + (size_t)((kt) * 64 + r0 + drow) * HDIM + dblk * 8), \
            (las_ptr)(Kd + r0 * 64), 16, 0, 0);                                \
        __builtin_amdgcn_global_load_lds(                                      \
            (gas_ptr)(vtbase + (size_t)(r0 + drow) * NN + (kt) * 64 + dblk * 8), \
            (las_ptr)(Vd + r0 * 64), 16, 0, 0);                                \
    }

    // Q B-fragments straight from global (row = this lane's query)
    const int myq = q0 + wave * 16 + l16;
    const unsigned short* qrow = qg + ((size_t)bh * NN + myq) * HDIM;
    const bf16x8 bQ0 = *(const bf16x8*)(qrow + quad * 8);
    const bf16x8 bQ1 = *(const bf16x8*)(qrow + quad * 8 + 32);

    bf16x4 ones4;
#pragma unroll
    for (int j = 0; j < 4; ++j) ones4[j] = (short)0x3F80;

    f32x4 O[4];
#pragma unroll
    for (int dt = 0; dt < 4; ++dt) O[dt] = (f32x4){0.f, 0.f, 0.f, 0.f};
    f32x4 lacc = (f32x4){0.f, 0.f, 0.f, 0.f};

    auto tile = [&](const unsigned short* Ks, const unsigned short* Vs, int kt) {
        const unsigned long long mreg = bitT[(size_t)kt * NN + myq];
        bf16x4 Pt[4];
#pragma unroll
        for (int nt = 0; nt < 4; ++nt) {
            bf16x8 aK0 = *(const bf16x8*)&Ks[(nt * 16 + l16) * 64 + bo0];
            bf16x8 aK1 = *(const bf16x8*)&Ks[(nt * 16 + l16) * 64 + bo1];
            f32x4 c = (f32x4){0.f, 0.f, 0.f, 0.f};
            c = MFMA32(aK0, bQ0, c);
            c = MFMA32(aK1, bQ1, c);
            const unsigned int mm = (unsigned int)(mreg >> (nt * 16 + quad * 4));
            float p0 = exp2f(c[0]); p0 = (mm & 1u)        ? p0 : 0.f;
            float p1 = exp2f(c[1]); p1 = ((mm >> 1) & 1u) ? p1 : 0.f;
            float p2 = exp2f(c[2]); p2 = ((mm >> 2) & 1u) ? p2 : 0.f;
            float p3 = exp2f(c[3]); p3 = ((mm >> 3) & 1u) ? p3 : 0.f;
            union { unsigned int u[2]; bf16x4 v; } cv;
            cv.u[0] = pack_trunc(p0, p1);
            cv.u[1] = pack_trunc(p2, p3);
            Pt[nt] = cv.v;
            lacc = MFMA16(ones4, Pt[nt], lacc);
        }
#pragma unroll
        for (int dt = 0; dt < 4; ++dt)
#pragma unroll
            for (int c4 = 0; c4 < 4; ++c4) {
                bf16x4 aV = *(const bf16x4*)&Vs[(dt * 16 + l16) * 64 + vofs[c4]];
                O[dt] = MFMA16(aV, Pt[c4], O[dt]);
            }
    };

    ATT_ISSUE(0, Ka, Va);
    for (int kk = 0; kk < 16; ++kk) {
        __syncthreads();
        ATT_ISSUE(2 * kk + 1, Kb, Vb);
        tile(Ka, Va, 2 * kk);
        __syncthreads();
        if (kk < 15) { ATT_ISSUE(2 * kk + 2, Ka, Va); }
        tile(Kb, Vb, 2 * kk + 1);
    }
    __syncthreads();   // all waves done reading K/V buffers

    // ---- epilogue: O^T -> per-wave LDS region -> coalesced bf16 out ----
    const float inv = 1.f / lacc[0];
    unsigned short* Lo = smem + wave * (16 * 72);
#pragma unroll
    for (int dt = 0; dt < 4; ++dt) {
        const float v0 = O[dt][0] * inv, v1 = O[dt][1] * inv;
        const float v2 = O[dt][2] * inv, v3 = O[dt][3] * inv;
        *(unsigned int*)&Lo[l16 * 72 + dt * 16 + quad * 4]     = pack_trunc(v0, v1);
        *(unsigned int*)&Lo[l16 * 72 + dt * 16 + quad * 4 + 2] = pack_trunc(v2, v3);
    }
    // same-wave read-back, coalesced 16B stores
    const int rr = lane >> 2;
    const int qq = q0 + wave * 16 + rr;
#pragma unroll
    for (int i = 0; i < 2; ++i) {
        const int ch = (lane & 3) + 4 * i;
        bf16x8 val = *(const bf16x8*)&Lo[rr * 72 + ch * 8];
        *(bf16x8*)(ao + ((size_t)(b * NN + qq)) * NOUT + h * HDIM + ch * 8) = val;
    }
#undef ATT_ISSUE
}

// ---------------------------------------------------------------------------
extern "C" void kernel_launch(void* const* d_in, const int* in_sizes, int n_in,
                              void* d_out, int out_size, void* d_ws, size_t ws_size,
                              hipStream_t stream)
{
    const float* x   = (const float*)d_in[0];
    const int*   adj = (const int*)  d_in[1];
    const float* Wq  = (const float*)d_in[2];
    const float* bq  = (const float*)d_in[3];
    const float* Wk  = (const float*)d_in[4];
    const float* bk  = (const float*)d_in[5];
    const float* Wv  = (const float*)d_in[6];
    const float* bv  = (const float*)d_in[7];
    const float* Wo  = (const float*)d_in[8];
    const float* bo  = (const float*)d_in[9];
    float* out = (float*)d_out;

    const size_t qkv_elems = (size_t)NB * NH * NN * HDIM;   // 4,194,304
    unsigned short* xb  = (unsigned short*)d_ws;
    unsigned short* q   = xb  + qkv_elems;
    unsigned short* kb  = q   + qkv_elems;
    unsigned short* vtb = kb  + qkv_elems;
    unsigned short* aob = vtb + qkv_elems;
    unsigned short* tWq = aob + qkv_elems;      // tWq/tWk/tWv contiguous
    unsigned short* tWk = tWq + (size_t)DD * NOUT;
    unsigned short* tWv = tWk + (size_t)DD * NOUT;
    unsigned short* tWo = tWv + (size_t)DD * NOUT;
    unsigned long long* bitsT = (unsigned long long*)(tWo + (size_t)DD * NOUT);

    prep<<<dim3(4352), 256, 0, stream>>>(x, xb, Wq, Wk, Wv, Wo,
                                         tWq, tWk, tWv, tWo, adj, bitsT);

    gemm_qkv<<<dim3(12, 64), 256, 0, stream>>>(xb, tWq, bq, bk, bv, q, kb, vtb);

    attn_mfma<<<dim3(NN / 128, NH, NB), 512, 0, stream>>>(q, kb, vtb, bitsT, aob);

    gemm_o<<<dim3(4, 64), 256, 0, stream>>>(aob, tWo, bo, out);
}

// Round 7
// 220.524 us; speedup vs baseline: 1.1753x; 1.1753x over previous
//
#include <hip/hip_runtime.h>
#include <math.h>

#define NB   4
#define NN   2048
#define DD   512
#define NOUT 512
#define NH   8
#define HDIM 64

typedef __attribute__((ext_vector_type(4))) short bf16x4;
typedef __attribute__((ext_vector_type(8))) short bf16x8;
typedef __attribute__((ext_vector_type(4))) float f32x4;
#define MFMA32(a, b, c)  __builtin_amdgcn_mfma_f32_16x16x32_bf16(a, b, c, 0, 0, 0)
#define MFMA16(a, b, c)  __builtin_amdgcn_mfma_f32_16x16x16bf16_1k(a, b, c, 0, 0, 0)

typedef const __attribute__((address_space(1))) unsigned int* gas_ptr;
typedef __attribute__((address_space(3))) unsigned int* las_ptr;

#define SCALE2 0.18033688f   /* 8^-1 * log2(e) */

// Fragment-tiled layout: T[blk128][kstep32][row128][32k]
//   flat = blk*65536 + ks*4096 + r*32 + kk
// A wave's MFMA fragment load (16 rows x 4 quad-chunks x 16B) is one
// CONTIGUOUS 1KB span -> fully coalesced global_load_dwordx4.

__device__ inline unsigned short f2bf(float f) {
    unsigned int u = __float_as_uint(f);
    u += 0x7fffu + ((u >> 16) & 1u);   // RNE
    return (unsigned short)(u >> 16);
}

// pack two fp32 -> two bf16 (truncation) in ONE v_perm
__device__ inline unsigned int pack_trunc(float lo, float hi) {
    return __builtin_amdgcn_perm(__float_as_uint(hi), __float_as_uint(lo), 0x07060302u);
}

// ---------------------------------------------------------------------------
// prep: convx (x -> bf16, fragment-tiled), transW (4 weights -> bf16
// transposed + fragment-tiled; q/k/v concatenated), pack_adj (bitsT[word][row]).
// ---------------------------------------------------------------------------
__global__ __launch_bounds__(256) void prep(
    const float* __restrict__ x, unsigned short* __restrict__ xt,
    const float* __restrict__ W0, const float* __restrict__ W1,
    const float* __restrict__ W2, const float* __restrict__ W3,
    unsigned short* __restrict__ Tqkv, unsigned short* __restrict__ To,
    const int* __restrict__ adj, unsigned long long* __restrict__ bitsT)
{
    const int blk = blockIdx.x;
    const int t   = threadIdx.x;

    if (blk < 2048) {                       // ---- convx -> tiled ----
        const int i = (blk * 256 + t) * 8;
        const int m = i >> 9, k = i & 511;
        float4 a = *(const float4*)(x + i);
        float4 b = *(const float4*)(x + i + 4);
        ushort4 u0, u1;
        u0.x = f2bf(a.x); u0.y = f2bf(a.y); u0.z = f2bf(a.z); u0.w = f2bf(a.w);
        u1.x = f2bf(b.x); u1.y = f2bf(b.y); u1.z = f2bf(b.z); u1.w = f2bf(b.w);
        unsigned short* dst = xt + ((size_t)(m >> 7) * 65536)
                                 + (k >> 5) * 4096 + (m & 127) * 32 + (k & 31);
        *(ushort4*)dst       = u0;
        *(ushort4*)(dst + 4) = u1;
        return;
    }
    if (blk < 2304) {                       // ---- transW -> tiled ----
        __shared__ float tile[64][65];
        const int idx = blk - 2048;
        const int z = idx >> 6, rem = idx & 63;
        const float* W;
        switch (z) {
            case 0:  W = W0; break;
            case 1:  W = W1; break;
            case 2:  W = W2; break;
            default: W = W3; break;
        }
        unsigned short* T = (z < 3) ? Tqkv : To;
        const int ngbase  = (z < 3) ? z * 512 : 0;
        const int k0 = (rem & 7) * 64, n0 = (rem >> 3) * 64;
        const int r = t >> 6, c = t & 63;
#pragma unroll
        for (int rep = 0; rep < 16; ++rep) {
            const int row = rep * 4 + r;
            tile[row][c] = W[(size_t)(k0 + row) * NOUT + n0 + c];
        }
        __syncthreads();
        const int k  = k0 + c;
        const int ks = k >> 5, kk = k & 31;
#pragma unroll
        for (int rep = 0; rep < 16; ++rep) {
            const int row = rep * 4 + r;          // n within this matrix
            const int ng  = ngbase + n0 + row;
            T[((size_t)(ng >> 7) * 65536) + ks * 4096 + (ng & 127) * 32 + kk]
                = f2bf(tile[c][row]);
        }
        return;
    }
    // ---- pack_adj: bitsT[word*2048 + row] ----
    {
        const int idx  = blk - 2304;
        const int wave = t >> 6, lane = t & 63;
        const int j    = idx * 4 + wave;          // 0..8191
        const int row  = j >> 2;
        const int wb   = (j & 3) * 8;
#pragma unroll
        for (int w = 0; w < 8; ++w) {
            const unsigned long long m =
                __ballot(adj[(size_t)row * NN + (wb + w) * 64 + lane] != 0);
            if (lane == 0) bitsT[(size_t)(wb + w) * NN + row] = m;
        }
    }
}

// ---------------------------------------------------------------------------
// Barrier-free, LDS-free GEMM on fragment-tiled inputs.
// 128x128 tile, 4 waves (64x64 each), 16 K-steps of 32.
// Register double-staging: loads for step k+1 issue before MFMAs of step k.
// ---------------------------------------------------------------------------
#define GT_SETUP(Atil, Wtil)                                                   \
    const int t = threadIdx.x, wave = t >> 6, lane = t & 63;                   \
    const int quad = lane >> 4, l16 = lane & 15;                               \
    const int n0 = blockIdx.x * 128, m0 = blockIdx.y * 128;                    \
    const int wm = (wave & 1) * 64, wn = (wave >> 1) * 64;                     \
    const unsigned short* aP[4];                                               \
    const unsigned short* bP[4];                                               \
    _Pragma("unroll")                                                          \
    for (int mt = 0; mt < 4; ++mt)                                             \
        aP[mt] = Atil + (size_t)blockIdx.y * 65536                             \
               + (wm + mt * 16 + l16) * 32 + quad * 8;                         \
    _Pragma("unroll")                                                          \
    for (int nt = 0; nt < 4; ++nt)                                             \
        bP[nt] = Wtil + (size_t)blockIdx.x * 65536                             \
               + (wn + nt * 16 + l16) * 32 + quad * 8;

#define GT_LOADF(Af, Bf, ks)                                                   \
    _Pragma("unroll")                                                          \
    for (int mt = 0; mt < 4; ++mt) Af[mt] = *(const bf16x8*)(aP[mt] + (ks) * 4096); \
    _Pragma("unroll")                                                          \
    for (int nt = 0; nt < 4; ++nt) Bf[nt] = *(const bf16x8*)(bP[nt] + (ks) * 4096);

#define GT_MFMA(Af, Bf)                                                        \
    _Pragma("unroll")                                                          \
    for (int mt = 0; mt < 4; ++mt)                                             \
        _Pragma("unroll")                                                      \
        for (int nt = 0; nt < 4; ++nt)                                         \
            acc[mt][nt] = MFMA32(Af[mt], Bf[nt], acc[mt][nt]);

#define GT_LOOP()                                                              \
    f32x4 acc[4][4];                                                           \
    _Pragma("unroll")                                                          \
    for (int mt = 0; mt < 4; ++mt)                                             \
        _Pragma("unroll")                                                      \
        for (int nt = 0; nt < 4; ++nt) acc[mt][nt] = (f32x4){0.f, 0.f, 0.f, 0.f}; \
    bf16x8 aA[4], bA[4], aB[4], bB[4];                                         \
    GT_LOADF(aA, bA, 0);                                                       \
    for (int kk = 0; kk < 8; ++kk) {                                           \
        GT_LOADF(aB, bB, 2 * kk + 1);                                          \
        GT_MFMA(aA, bA);                                                       \
        if (kk < 7) { GT_LOADF(aA, bA, 2 * kk + 2); }                          \
        GT_MFMA(aB, bB);                                                       \
    }

// ---------------------------------------------------------------------------
// Fused QKV GEMM: seg0 -> q bf16 [B,H,N,64] PRE-SCALED by SCALE2;
// seg1 -> k same; seg2 -> v^T [B,H,64,N].
// ---------------------------------------------------------------------------
__global__ __launch_bounds__(256, 3) void gemm_qkv(
    const unsigned short* __restrict__ Atil,
    const unsigned short* __restrict__ Wtil,
    const float* __restrict__ bq, const float* __restrict__ bk,
    const float* __restrict__ bv,
    unsigned short* __restrict__ qo, unsigned short* __restrict__ ko,
    unsigned short* __restrict__ vto)
{
    GT_SETUP(Atil, Wtil);
    GT_LOOP();

    const int seg   = n0 >> 9;           // 0:q 1:k 2:v
    const int nloc0 = n0 & 511;
    const float* bp = (seg == 0) ? bq : (seg == 1) ? bk : bv;
    unsigned short* dst3 = (seg == 0) ? qo : (seg == 1) ? ko : vto;

    float bias4[4];
#pragma unroll
    for (int nt = 0; nt < 4; ++nt) bias4[nt] = bp[nloc0 + wn + nt * 16 + l16];

#pragma unroll
    for (int mt = 0; mt < 4; ++mt) {
#pragma unroll
        for (int nt = 0; nt < 4; ++nt) {
            const int lcol = nloc0 + wn + nt * 16 + l16;
            const int h = lcol >> 6, d = lcol & 63;
#pragma unroll
            for (int r = 0; r < 4; ++r) {
                const int row = m0 + wm + mt * 16 + quad * 4 + r;
                const int bb = row >> 11, n = row & (NN - 1);
                float val = acc[mt][nt][r] + bias4[nt];
                if (seg == 0) val *= SCALE2;
                if (seg < 2)
                    dst3[((size_t)(bb * NH + h) * NN + n) * HDIM + d] = f2bf(val);
                else
                    dst3[((size_t)(bb * NH + h) * HDIM + d) * NN + n] = f2bf(val);
            }
        }
    }
}

// ---------------------------------------------------------------------------
// O-projection GEMM: out fp32 [8192,512] (A = attn output, fragment-tiled)
// ---------------------------------------------------------------------------
__global__ __launch_bounds__(256, 3) void gemm_o(
    const unsigned short* __restrict__ Atil,
    const unsigned short* __restrict__ Wtil,
    const float* __restrict__ bias,
    float* __restrict__ C)
{
    GT_SETUP(Atil, Wtil);
    GT_LOOP();

    float bias4[4];
#pragma unroll
    for (int nt = 0; nt < 4; ++nt) bias4[nt] = bias[n0 + wn + nt * 16 + l16];

#pragma unroll
    for (int mt = 0; mt < 4; ++mt)
#pragma unroll
        for (int nt = 0; nt < 4; ++nt) {
            const int col = n0 + wn + nt * 16 + l16;
#pragma unroll
            for (int r = 0; r < 4; ++r) {
                const int row = m0 + wm + mt * 16 + quad * 4 + r;
                C[(size_t)row * NOUT + col] = acc[mt][nt][r] + bias4[nt];
            }
        }
}

// ---------------------------------------------------------------------------
// MFMA flash attention, transposed-score formulation, 8-wave blocks.
// Output written in fragment-tiled layout for gemm_o.
// ---------------------------------------------------------------------------
__global__ __launch_bounds__(512) void attn_mfma(
    const unsigned short* __restrict__ qg,
    const unsigned short* __restrict__ kg,
    const unsigned short* __restrict__ vt,
    const unsigned long long* __restrict__ bitT,   // [word][row]
    unsigned short* __restrict__ aot)
{
    __shared__ unsigned short smem[4 * 64 * 64];   // Ka | Va | Kb | Vb (32 KB)
    unsigned short* Ka = smem;
    unsigned short* Va = smem + 4096;
    unsigned short* Kb = smem + 8192;
    unsigned short* Vb = smem + 12288;

    const int t    = threadIdx.x;
    const int wave = t >> 6;
    const int lane = t & 63;
    const int quad = lane >> 4;
    const int l16  = lane & 15;

    const int qt = blockIdx.x, h = blockIdx.y, b = blockIdx.z;
    const int bh = b * NH + h;
    const int q0 = qt * 128;

    const unsigned short* kbase  = kg + (size_t)bh * NN * HDIM;
    const unsigned short* vtbase = vt + (size_t)bh * HDIM * NN;

    // DMA swizzle (16B blocks): physical blk = logical blk ^ (row & 7)
    const int drow = lane >> 3;
    const int dblk = (lane & 7) ^ drow;

    // fragment-read swizzle offsets
    const int sw  = l16 & 7;
    const int bo0 = (quad ^ sw) * 8;         // K chunk0 (16B)
    const int bo1 = bo0 ^ 32;                // K chunk1
    int vofs[4];
#pragma unroll
    for (int c = 0; c < 4; ++c)
        vofs[c] = (((c * 2 + (quad >> 1)) ^ sw) * 8) + (quad & 1) * 4;  // V 8B frags

#define ATT_ISSUE(kt, Kd, Vd)                                                  \
    {                                                                          \
        const int r0 = wave * 8;                                               \
        __builtin_amdgcn_global_load_lds(                                      \
            (gas_ptr)(kbase + (size_t)((kt) * 64 + r0 + drow) * HDIM + dblk * 8), \
            (las_ptr)(Kd + r0 * 64), 16, 0, 0);                                \
        __builtin_amdgcn_global_load_lds(                                      \
            (gas_ptr)(vtbase + (size_t)(r0 + drow) * NN + (kt) * 64 + dblk * 8), \
            (las_ptr)(Vd + r0 * 64), 16, 0, 0);                                \
    }

    // Q B-fragments straight from global (row = this lane's query)
    const int myq = q0 + wave * 16 + l16;
    const unsigned short* qrow = qg + ((size_t)bh * NN + myq) * HDIM;
    const bf16x8 bQ0 = *(const bf16x8*)(qrow + quad * 8);
    const bf16x8 bQ1 = *(const bf16x8*)(qrow + quad * 8 + 32);

    bf16x4 ones4;
#pragma unroll
    for (int j = 0; j < 4; ++j) ones4[j] = (short)0x3F80;

    f32x4 O[4];
#pragma unroll
    for (int dt = 0; dt < 4; ++dt) O[dt] = (f32x4){0.f, 0.f, 0.f, 0.f};
    f32x4 lacc = (f32x4){0.f, 0.f, 0.f, 0.f};

    auto tile = [&](const unsigned short* Ks, const unsigned short* Vs, int kt) {
        const unsigned long long mreg = bitT[(size_t)kt * NN + myq];
        bf16x4 Pt[4];
#pragma unroll
        for (int nt = 0; nt < 4; ++nt) {
            bf16x8 aK0 = *(const bf16x8*)&Ks[(nt * 16 + l16) * 64 + bo0];
            bf16x8 aK1 = *(const bf16x8*)&Ks[(nt * 16 + l16) * 64 + bo1];
            f32x4 c = (f32x4){0.f, 0.f, 0.f, 0.f};
            c = MFMA32(aK0, bQ0, c);
            c = MFMA32(aK1, bQ1, c);
            const unsigned int mm = (unsigned int)(mreg >> (nt * 16 + quad * 4));
            float p0 = exp2f(c[0]); p0 = (mm & 1u)        ? p0 : 0.f;
            float p1 = exp2f(c[1]); p1 = ((mm >> 1) & 1u) ? p1 : 0.f;
            float p2 = exp2f(c[2]); p2 = ((mm >> 2) & 1u) ? p2 : 0.f;
            float p3 = exp2f(c[3]); p3 = ((mm >> 3) & 1u) ? p3 : 0.f;
            union { unsigned int u[2]; bf16x4 v; } cv;
            cv.u[0] = pack_trunc(p0, p1);
            cv.u[1] = pack_trunc(p2, p3);
            Pt[nt] = cv.v;
            lacc = MFMA16(ones4, Pt[nt], lacc);
        }
#pragma unroll
        for (int dt = 0; dt < 4; ++dt)
#pragma unroll
            for (int c4 = 0; c4 < 4; ++c4) {
                bf16x4 aV = *(const bf16x4*)&Vs[(dt * 16 + l16) * 64 + vofs[c4]];
                O[dt] = MFMA16(aV, Pt[c4], O[dt]);
            }
    };

    ATT_ISSUE(0, Ka, Va);
    for (int kk = 0; kk < 16; ++kk) {
        __syncthreads();
        ATT_ISSUE(2 * kk + 1, Kb, Vb);
        tile(Ka, Va, 2 * kk);
        __syncthreads();
        if (kk < 15) { ATT_ISSUE(2 * kk + 2, Ka, Va); }
        tile(Kb, Vb, 2 * kk + 1);
    }
    __syncthreads();   // all waves done reading K/V buffers

    // ---- epilogue: O^T -> per-wave LDS region -> tiled bf16 out ----
    const float inv = 1.f / lacc[0];
    unsigned short* Lo = smem + wave * (16 * 72);
#pragma unroll
    for (int dt = 0; dt < 4; ++dt) {
        const float v0 = O[dt][0] * inv, v1 = O[dt][1] * inv;
        const float v2 = O[dt][2] * inv, v3 = O[dt][3] * inv;
        *(unsigned int*)&Lo[l16 * 72 + dt * 16 + quad * 4]     = pack_trunc(v0, v1);
        *(unsigned int*)&Lo[l16 * 72 + dt * 16 + quad * 4 + 2] = pack_trunc(v2, v3);
    }
    // same-wave read-back -> fragment-tiled store (64B/4-lane group, coalesced)
    const int rr = lane >> 2;
    const int qq = q0 + wave * 16 + rr;
    const int m  = b * NN + qq;
    const int mb = m >> 7, r = m & 127;
#pragma unroll
    for (int i = 0; i < 2; ++i) {
        const int ch = (lane & 3) + 4 * i;            // 0..7 (d = ch*8)
        const int ks = h * 2 + (ch >> 2);
        bf16x8 val = *(const bf16x8*)&Lo[rr * 72 + ch * 8];
        *(bf16x8*)(aot + (size_t)mb * 65536 + ks * 4096 + r * 32 + (ch & 3) * 8) = val;
    }
#undef ATT_ISSUE
}

// ---------------------------------------------------------------------------
extern "C" void kernel_launch(void* const* d_in, const int* in_sizes, int n_in,
                              void* d_out, int out_size, void* d_ws, size_t ws_size,
                              hipStream_t stream)
{
    const float* x   = (const float*)d_in[0];
    const int*   adj = (const int*)  d_in[1];
    const float* Wq  = (const float*)d_in[2];
    const float* bq  = (const float*)d_in[3];
    const float* Wk  = (const float*)d_in[4];
    const float* bk  = (const float*)d_in[5];
    const float* Wv  = (const float*)d_in[6];
    const float* bv  = (const float*)d_in[7];
    const float* Wo  = (const float*)d_in[8];
    const float* bo  = (const float*)d_in[9];
    float* out = (float*)d_out;

    const size_t qkv_elems = (size_t)NB * NH * NN * HDIM;   // 4,194,304
    unsigned short* xt   = (unsigned short*)d_ws;            // x, tiled
    unsigned short* q    = xt   + qkv_elems;
    unsigned short* kb   = q    + qkv_elems;
    unsigned short* vtb  = kb   + qkv_elems;
    unsigned short* aot  = vtb  + qkv_elems;                 // attn out, tiled
    unsigned short* tWqkv= aot  + qkv_elems;                 // 1536x512 tiled
    unsigned short* tWo  = tWqkv + (size_t)3 * DD * NOUT;    // 512x512 tiled
    unsigned long long* bitsT = (unsigned long long*)(tWo + (size_t)DD * NOUT);

    prep<<<dim3(4352), 256, 0, stream>>>(x, xt, Wq, Wk, Wv, Wo,
                                         tWqkv, tWo, adj, bitsT);

    gemm_qkv<<<dim3(12, 64), 256, 0, stream>>>(xt, tWqkv, bq, bk, bv, q, kb, vtb);

    attn_mfma<<<dim3(NN / 128, NH, NB), 512, 0, stream>>>(q, kb, vtb, bitsT, aot);

    gemm_o<<<dim3(4, 64), 256, 0, stream>>>(aot, tWo, bo, out);
}

// Round 8
// 195.868 us; speedup vs baseline: 1.3233x; 1.1259x over previous
//
#include <hip/hip_runtime.h>
#include <math.h>

#define NB   4
#define NN   2048
#define DD   512
#define NOUT 512
#define NH   8
#define HDIM 64

typedef __attribute__((ext_vector_type(4))) short bf16x4;
typedef __attribute__((ext_vector_type(8))) short bf16x8;
typedef __attribute__((ext_vector_type(4))) float f32x4;
#define MFMA32(a, b, c)  __builtin_amdgcn_mfma_f32_16x16x32_bf16(a, b, c, 0, 0, 0)

typedef const __attribute__((address_space(1))) unsigned int* gas_ptr;
typedef __attribute__((address_space(3))) unsigned int* las_ptr;

#define SCALE2 0.18033688f   /* 8^-1 * log2(e) */

// Fragment-tiled layout: T[blk128][kstep32][row128][32k]
//   flat = blk*65536 + ks*4096 + r*32 + kk

__device__ inline unsigned short f2bf(float f) {
    unsigned int u = __float_as_uint(f);
    u += 0x7fffu + ((u >> 16) & 1u);   // RNE
    return (unsigned short)(u >> 16);
}

// pack two fp32 -> two bf16 (truncation) in ONE v_perm
__device__ inline unsigned int pack_trunc(float lo, float hi) {
    return __builtin_amdgcn_perm(__float_as_uint(hi), __float_as_uint(lo), 0x07060302u);
}

// ---------------------------------------------------------------------------
// prep: convx (x -> bf16, fragment-tiled), transW (weights -> bf16 transposed
// + tiled), amask (adj -> u32 AND-words: word w of row q = 0xFFFF per live
// key {2w,2w+1}).
// ---------------------------------------------------------------------------
__global__ __launch_bounds__(256) void prep(
    const float* __restrict__ x, unsigned short* __restrict__ xt,
    const float* __restrict__ W0, const float* __restrict__ W1,
    const float* __restrict__ W2, const float* __restrict__ W3,
    unsigned short* __restrict__ Tqkv, unsigned short* __restrict__ To,
    const int* __restrict__ adj, unsigned int* __restrict__ amaskW)
{
    const int blk = blockIdx.x;
    const int t   = threadIdx.x;

    if (blk < 2048) {                       // ---- convx -> tiled ----
        const int i = (blk * 256 + t) * 8;
        const int m = i >> 9, k = i & 511;
        float4 a = *(const float4*)(x + i);
        float4 b = *(const float4*)(x + i + 4);
        ushort4 u0, u1;
        u0.x = f2bf(a.x); u0.y = f2bf(a.y); u0.z = f2bf(a.z); u0.w = f2bf(a.w);
        u1.x = f2bf(b.x); u1.y = f2bf(b.y); u1.z = f2bf(b.z); u1.w = f2bf(b.w);
        unsigned short* dst = xt + ((size_t)(m >> 7) * 65536)
                                 + (k >> 5) * 4096 + (m & 127) * 32 + (k & 31);
        *(ushort4*)dst       = u0;
        *(ushort4*)(dst + 4) = u1;
        return;
    }
    if (blk < 2304) {                       // ---- transW -> tiled ----
        __shared__ float tile[64][65];
        const int idx = blk - 2048;
        const int z = idx >> 6, rem = idx & 63;
        const float* W;
        switch (z) {
            case 0:  W = W0; break;
            case 1:  W = W1; break;
            case 2:  W = W2; break;
            default: W = W3; break;
        }
        unsigned short* T = (z < 3) ? Tqkv : To;
        const int ngbase  = (z < 3) ? z * 512 : 0;
        const int k0 = (rem & 7) * 64, n0 = (rem >> 3) * 64;
        const int r = t >> 6, c = t & 63;
#pragma unroll
        for (int rep = 0; rep < 16; ++rep) {
            const int row = rep * 4 + r;
            tile[row][c] = W[(size_t)(k0 + row) * NOUT + n0 + c];
        }
        __syncthreads();
        const int k  = k0 + c;
        const int ks = k >> 5, kk = k & 31;
#pragma unroll
        for (int rep = 0; rep < 16; ++rep) {
            const int row = rep * 4 + r;          // n within this matrix
            const int ng  = ngbase + n0 + row;
            T[((size_t)(ng >> 7) * 65536) + ks * 4096 + (ng & 127) * 32 + kk]
                = f2bf(tile[c][row]);
        }
        return;
    }
    // ---- amask: 4 u32 words (8 keys) per thread ----
    {
        const int gid  = (blk - 2304) * 256 + t;   // 0..524287
        const int w0   = gid * 4;
        const int qrow = w0 >> 10;
        const int wloc = w0 & 1023;
        const int kb0  = wloc * 2;
        int4 a0 = *(const int4*)(adj + (size_t)qrow * NN + kb0);
        int4 a1 = *(const int4*)(adj + (size_t)qrow * NN + kb0 + 4);
        uint4 m;
        m.x = (a0.x ? 0xFFFFu : 0u) | (a0.y ? 0xFFFF0000u : 0u);
        m.y = (a0.z ? 0xFFFFu : 0u) | (a0.w ? 0xFFFF0000u : 0u);
        m.z = (a1.x ? 0xFFFFu : 0u) | (a1.y ? 0xFFFF0000u : 0u);
        m.w = (a1.z ? 0xFFFFu : 0u) | (a1.w ? 0xFFFF0000u : 0u);
        *(uint4*)(amaskW + (size_t)qrow * 1024 + wloc) = m;
    }
}

// ---------------------------------------------------------------------------
// Barrier-free, LDS-free GEMM K-loop on fragment-tiled inputs (128x128).
// ---------------------------------------------------------------------------
#define GT_SETUP(Atil, Wtil)                                                   \
    const int t = threadIdx.x, wave = t >> 6, lane = t & 63;                   \
    const int quad = lane >> 4, l16 = lane & 15;                               \
    const int n0 = blockIdx.x * 128, m0 = blockIdx.y * 128;                    \
    const int wm = (wave & 1) * 64, wn = (wave >> 1) * 64;                     \
    const unsigned short* aP[4];                                               \
    const unsigned short* bP[4];                                               \
    _Pragma("unroll")                                                          \
    for (int mt = 0; mt < 4; ++mt)                                             \
        aP[mt] = Atil + (size_t)blockIdx.y * 65536                             \
               + (wm + mt * 16 + l16) * 32 + quad * 8;                         \
    _Pragma("unroll")                                                          \
    for (int nt = 0; nt < 4; ++nt)                                             \
        bP[nt] = Wtil + (size_t)blockIdx.x * 65536                             \
               + (wn + nt * 16 + l16) * 32 + quad * 8;

#define GT_LOADF(Af, Bf, NTC, ks)                                              \
    _Pragma("unroll")                                                          \
    for (int mt = 0; mt < 4; ++mt) Af[mt] = *(const bf16x8*)(aP[mt] + (ks) * 4096); \
    _Pragma("unroll")                                                          \
    for (int nt = 0; nt < NTC; ++nt) Bf[nt] = *(const bf16x8*)(bP[nt] + (ks) * 4096);

#define GT_MFMA(Af, Bf, NTC)                                                   \
    _Pragma("unroll")                                                          \
    for (int mt = 0; mt < 4; ++mt)                                             \
        _Pragma("unroll")                                                      \
        for (int nt = 0; nt < NTC; ++nt)                                       \
            acc[mt][nt] = MFMA32(Af[mt], Bf[nt], acc[mt][nt]);

#define GT_LOOP(NTC)                                                           \
    f32x4 acc[4][NTC];                                                         \
    _Pragma("unroll")                                                          \
    for (int mt = 0; mt < 4; ++mt)                                             \
        _Pragma("unroll")                                                      \
        for (int nt = 0; nt < NTC; ++nt) acc[mt][nt] = (f32x4){0.f, 0.f, 0.f, 0.f}; \
    bf16x8 aA[4], bA[NTC], aB[4], bB[NTC];                                     \
    GT_LOADF(aA, bA, NTC, 0);                                                  \
    for (int kk = 0; kk < 8; ++kk) {                                           \
        GT_LOADF(aB, bB, NTC, 2 * kk + 1);                                     \
        GT_MFMA(aA, bA, NTC);                                                  \
        if (kk < 7) { GT_LOADF(aA, bA, NTC, 2 * kk + 2); }                     \
        GT_MFMA(aB, bB, NTC);                                                  \
    }

// ---------------------------------------------------------------------------
// Fused QKV GEMM. Coalesced epilogue via per-wave LDS round-trip.
// seg0 -> q bf16 [B,H,N,64] pre-scaled by SCALE2; seg1 -> k; seg2 -> v^T.
// ---------------------------------------------------------------------------
__global__ __launch_bounds__(256, 3) void gemm_qkv(
    const unsigned short* __restrict__ Atil,
    const unsigned short* __restrict__ Wtil,
    const float* __restrict__ bq, const float* __restrict__ bk,
    const float* __restrict__ bv,
    unsigned short* __restrict__ qo, unsigned short* __restrict__ ko,
    unsigned short* __restrict__ vto)
{
    __shared__ unsigned short eps[4 * 2560];   // per-wave epilogue region (20KB)
    GT_SETUP(Atil, Wtil);
    GT_LOOP(4);

    const int seg   = n0 >> 9;           // 0:q 1:k 2:v
    const int nloc0 = n0 & 511;
    const float* bp = (seg == 0) ? bq : (seg == 1) ? bk : bv;
    unsigned short* dst3 = (seg == 0) ? qo : (seg == 1) ? ko : vto;
    const int h = (nloc0 + wn) >> 6;     // wave's 64 cols = one head

    float bias4[4];
#pragma unroll
    for (int nt = 0; nt < 4; ++nt) bias4[nt] = bp[nloc0 + wn + nt * 16 + l16];

    unsigned short* Lo = eps + wave * 2560;
#pragma unroll
    for (int mt = 0; mt < 4; ++mt) {
        if (seg < 2) {
            // region [16 m][72 d-pad], C-layout scatter -> row-coalesced out
#pragma unroll
            for (int nt = 0; nt < 4; ++nt)
#pragma unroll
                for (int r = 0; r < 4; ++r) {
                    float val = acc[mt][nt][r] + bias4[nt];
                    if (seg == 0) val *= SCALE2;
                    Lo[(quad * 4 + r) * 72 + nt * 16 + l16] = f2bf(val);
                }
#pragma unroll
            for (int pass = 0; pass < 2; ++pass) {
                const int row = pass * 8 + (lane >> 3);
                const int mg  = m0 + wm + mt * 16 + row;
                const int bb  = mg >> 11, n = mg & (NN - 1);
                bf16x8 v = *(const bf16x8*)&Lo[row * 72 + (lane & 7) * 8];
                *(bf16x8*)(dst3 + ((size_t)(bb * NH + h) * NN + n) * HDIM
                           + (lane & 7) * 8) = v;
            }
        } else {
            // region [64 d][40-pad m], transposed scatter -> d-row out
#pragma unroll
            for (int nt = 0; nt < 4; ++nt)
#pragma unroll
                for (int r = 0; r < 4; ++r) {
                    const float val = acc[mt][nt][r] + bias4[nt];
                    Lo[(nt * 16 + l16) * 40 + quad * 4 + r] = f2bf(val);
                }
            const int d  = lane;
            const int mg = m0 + wm + mt * 16;
            const int bb = mg >> 11, n = mg & (NN - 1);
            unsigned short* dr = dst3 + ((size_t)(bb * NH + h) * HDIM + d) * NN + n;
            *(bf16x8*)dr       = *(const bf16x8*)&Lo[d * 40];
            *(bf16x8*)(dr + 8) = *(const bf16x8*)&Lo[d * 40 + 8];
        }
    }
}

// ---------------------------------------------------------------------------
// O-projection GEMM: 128x64 tiles (512 blocks, 2/CU), out fp32 [8192,512]
// ---------------------------------------------------------------------------
__global__ __launch_bounds__(256, 3) void gemm_o(
    const unsigned short* __restrict__ Atil,
    const unsigned short* __restrict__ Wtil,
    const float* __restrict__ bias,
    float* __restrict__ C)
{
    const int t = threadIdx.x, wave = t >> 6, lane = t & 63;
    const int quad = lane >> 4, l16 = lane & 15;
    const int n0 = blockIdx.x * 64, m0 = blockIdx.y * 128;
    const int wm = (wave & 1) * 64, wn = (wave >> 1) * 32;
    const unsigned short* aP[4];
    const unsigned short* bP[2];
#pragma unroll
    for (int mt = 0; mt < 4; ++mt)
        aP[mt] = Atil + (size_t)blockIdx.y * 65536
               + (wm + mt * 16 + l16) * 32 + quad * 8;
#pragma unroll
    for (int nt = 0; nt < 2; ++nt)
        bP[nt] = Wtil + (size_t)(n0 >> 7) * 65536
               + ((n0 & 64) + wn + nt * 16 + l16) * 32 + quad * 8;

    GT_LOOP(2);

    float bias2[2];
#pragma unroll
    for (int nt = 0; nt < 2; ++nt) bias2[nt] = bias[n0 + wn + nt * 16 + l16];

#pragma unroll
    for (int mt = 0; mt < 4; ++mt)
#pragma unroll
        for (int nt = 0; nt < 2; ++nt) {
            const int col = n0 + wn + nt * 16 + l16;
#pragma unroll
            for (int r = 0; r < 4; ++r) {
                const int row = m0 + wm + mt * 16 + quad * 4 + r;
                C[(size_t)row * NOUT + col] = acc[mt][nt][r] + bias2[nt];
            }
        }
}

// ---------------------------------------------------------------------------
// MFMA flash attention — all-K=32 formulation via key permutation.
// Staged K row p holds logical key L(p)=chunk*32+quad*8+ntlow*4+r, so the
// QK^T C-layout P^T registers are EXACTLY mfma32's B operand per 32-key
// chunk: PV = 8 MFMA32/tile, lsum = 2 MFMA32/tile. Masking = one v_and per
// packed P pair against precomputed AND-words (prefetched a tile ahead).
// ---------------------------------------------------------------------------
__global__ __launch_bounds__(512) void attn_mfma(
    const unsigned short* __restrict__ qg,
    const unsigned short* __restrict__ kg,
    const unsigned short* __restrict__ vt,
    const unsigned int* __restrict__ amask,   // [q][1024] u32 AND-words
    unsigned short* __restrict__ aot)
{
    __shared__ unsigned short smem[4 * 64 * 64];   // Ka | Va | Kb | Vb (32 KB)
    unsigned short* Ka = smem;
    unsigned short* Va = smem + 4096;
    unsigned short* Kb = smem + 8192;
    unsigned short* Vb = smem + 12288;

    const int t    = threadIdx.x;
    const int wave = t >> 6;
    const int lane = t & 63;
    const int quad = lane >> 4;
    const int l16  = lane & 15;

    const int qt = blockIdx.x, h = blockIdx.y, b = blockIdx.z;
    const int bh = b * NH + h;
    const int q0 = qt * 128;

    const unsigned short* kbase  = kg + (size_t)bh * NN * HDIM;
    const unsigned short* vtbase = vt + (size_t)bh * HDIM * NN;

    // DMA swizzle (16B blocks): physical blk = logical blk ^ (row & 7)
    const int drow = lane >> 3;
    const int dblk = (lane & 7) ^ drow;
    // key permutation: physical LDS row p holds logical key L(p)
    const int p  = wave * 8 + drow;
    const int Lp = (p & 32) + ((p >> 2) & 3) * 8 + ((p >> 4) & 1) * 4 + (p & 3);

    // fragment-read swizzle offsets
    const int sw  = l16 & 7;
    const int bo0 = (quad ^ sw) * 8;         // K d-chunk0 (16B)
    const int bo1 = bo0 ^ 32;                // K d-chunk1

#define ATT_ISSUE(kt, Kd, Vd)                                                  \
    {                                                                          \
        const int r0 = wave * 8;                                               \
        __builtin_amdgcn_global_load_lds(                                      \
            (gas_ptr)(kbase + (size_t)((kt) * 64 + Lp) * HDIM + dblk * 8),     \
            (las_ptr)(Kd + r0 * 64), 16, 0, 0);                                \
        __builtin_amdgcn_global_load_lds(                                      \
            (gas_ptr)(vtbase + (size_t)(r0 + drow) * NN + (kt) * 64 + dblk * 8), \
            (las_ptr)(Vd + r0 * 64), 16, 0, 0);                                \
    }

    // Q B-fragments straight from global (row = this lane's query)
    const int myq = q0 + wave * 16 + l16;
    const unsigned short* qrow = qg + ((size_t)bh * NN + myq) * HDIM;
    const bf16x8 bQ0 = *(const bf16x8*)(qrow + quad * 8);
    const bf16x8 bQ1 = *(const bf16x8*)(qrow + quad * 8 + 32);

    const unsigned int* mrow = amask + (size_t)myq * 1024 + quad * 4;
#define MLOAD(kt, c) (*(const uint4*)(mrow + (kt) * 32 + (c) * 16))

    bf16x8 ones8;
#pragma unroll
    for (int j = 0; j < 8; ++j) ones8[j] = (short)0x3F80;

    f32x4 O[4];
#pragma unroll
    for (int dt = 0; dt < 4; ++dt) O[dt] = (f32x4){0.f, 0.f, 0.f, 0.f};
    f32x4 lacc = (f32x4){0.f, 0.f, 0.f, 0.f};

    auto tile = [&](const unsigned short* Ks, const unsigned short* Vs,
                    uint4 mw0, uint4 mw1) {
        bf16x8 Pt[2];
#pragma unroll
        for (int c = 0; c < 2; ++c) {
            const uint4 mw = c ? mw1 : mw0;
            union { unsigned int u[4]; bf16x8 v; } cv;
#pragma unroll
            for (int half = 0; half < 2; ++half) {
                const int nt = c * 2 + half;
                bf16x8 aK0 = *(const bf16x8*)&Ks[(nt * 16 + l16) * 64 + bo0];
                bf16x8 aK1 = *(const bf16x8*)&Ks[(nt * 16 + l16) * 64 + bo1];
                f32x4 s = (f32x4){0.f, 0.f, 0.f, 0.f};
                s = MFMA32(aK0, bQ0, s);
                s = MFMA32(aK1, bQ1, s);
                const float p0 = exp2f(s[0]);
                const float p1 = exp2f(s[1]);
                const float p2 = exp2f(s[2]);
                const float p3 = exp2f(s[3]);
                cv.u[half * 2 + 0] = pack_trunc(p0, p1) & (half ? mw.z : mw.x);
                cv.u[half * 2 + 1] = pack_trunc(p2, p3) & (half ? mw.w : mw.y);
            }
            Pt[c] = cv.v;
            lacc = MFMA32(ones8, Pt[c], lacc);
        }
#pragma unroll
        for (int dt = 0; dt < 4; ++dt)
#pragma unroll
            for (int c = 0; c < 2; ++c) {
                bf16x8 aV = *(const bf16x8*)
                    &Vs[(dt * 16 + l16) * 64 + (((c * 4 + quad) ^ sw) * 8)];
                O[dt] = MFMA32(aV, Pt[c], O[dt]);
            }
    };

    uint4 mA0 = MLOAD(0, 0), mA1 = MLOAD(0, 1);
    uint4 mB0, mB1;
    ATT_ISSUE(0, Ka, Va);
    for (int kk = 0; kk < 16; ++kk) {
        __syncthreads();
        ATT_ISSUE(2 * kk + 1, Kb, Vb);
        mB0 = MLOAD(2 * kk + 1, 0); mB1 = MLOAD(2 * kk + 1, 1);
        tile(Ka, Va, mA0, mA1);
        __syncthreads();
        if (kk < 15) {
            ATT_ISSUE(2 * kk + 2, Ka, Va);
            mA0 = MLOAD(2 * kk + 2, 0); mA1 = MLOAD(2 * kk + 2, 1);
        }
        tile(Kb, Vb, mB0, mB1);
    }
    __syncthreads();   // all waves done reading K/V buffers

    // ---- epilogue: O^T -> per-wave LDS region -> fragment-tiled bf16 out ----
    const float inv = 1.f / lacc[0];
    unsigned short* Lo = smem + wave * (16 * 72);
#pragma unroll
    for (int dt = 0; dt < 4; ++dt) {
        const float v0 = O[dt][0] * inv, v1 = O[dt][1] * inv;
        const float v2 = O[dt][2] * inv, v3 = O[dt][3] * inv;
        *(unsigned int*)&Lo[l16 * 72 + dt * 16 + quad * 4]     = pack_trunc(v0, v1);
        *(unsigned int*)&Lo[l16 * 72 + dt * 16 + quad * 4 + 2] = pack_trunc(v2, v3);
    }
    const int rr = lane >> 2;
    const int qq = q0 + wave * 16 + rr;
    const int m  = b * NN + qq;
    const int mb = m >> 7, r = m & 127;
#pragma unroll
    for (int i = 0; i < 2; ++i) {
        const int ch = (lane & 3) + 4 * i;            // 0..7 (d = ch*8)
        const int ks = h * 2 + (ch >> 2);
        bf16x8 val = *(const bf16x8*)&Lo[rr * 72 + ch * 8];
        *(bf16x8*)(aot + (size_t)mb * 65536 + ks * 4096 + r * 32 + (ch & 3) * 8) = val;
    }
#undef ATT_ISSUE
#undef MLOAD
}

// ---------------------------------------------------------------------------
extern "C" void kernel_launch(void* const* d_in, const int* in_sizes, int n_in,
                              void* d_out, int out_size, void* d_ws, size_t ws_size,
                              hipStream_t stream)
{
    const float* x   = (const float*)d_in[0];
    const int*   adj = (const int*)  d_in[1];
    const float* Wq  = (const float*)d_in[2];
    const float* bq  = (const float*)d_in[3];
    const float* Wk  = (const float*)d_in[4];
    const float* bk  = (const float*)d_in[5];
    const float* Wv  = (const float*)d_in[6];
    const float* bv  = (const float*)d_in[7];
    const float* Wo  = (const float*)d_in[8];
    const float* bo  = (const float*)d_in[9];
    float* out = (float*)d_out;

    const size_t qkv_elems = (size_t)NB * NH * NN * HDIM;   // 4,194,304
    unsigned short* xt    = (unsigned short*)d_ws;           // x tiled; reused as aot
    unsigned short* q     = xt   + qkv_elems;
    unsigned short* kb    = q    + qkv_elems;
    unsigned short* vtb   = kb   + qkv_elems;
    unsigned short* tWqkv = vtb  + qkv_elems;                // 1536x512 tiled
    unsigned short* tWo   = tWqkv + (size_t)3 * DD * NOUT;   // 512x512 tiled
    unsigned int*   amaskW = (unsigned int*)(tWo + (size_t)DD * NOUT);  // 8MB
    unsigned short* aot   = xt;                              // alias (xt dead after QKV)

    prep<<<dim3(4352), 256, 0, stream>>>(x, xt, Wq, Wk, Wv, Wo,
                                         tWqkv, tWo, adj, amaskW);

    gemm_qkv<<<dim3(12, 64), 256, 0, stream>>>(xt, tWqkv, bq, bk, bv, q, kb, vtb);

    attn_mfma<<<dim3(NN / 128, NH, NB), 512, 0, stream>>>(q, kb, vtb, amaskW, aot);

    gemm_o<<<dim3(8, 64), 256, 0, stream>>>(aot, tWo, bo, out);
}